// Round 17
// baseline (66.381 us; speedup 1.0000x reference)
//
#include <hip/hip_runtime.h>
#include <hip/hip_bf16.h>

#define WB 8192
#define WD 128
#define WC 100
#define NSPLIT 64
#define JSPL (WB/NSPLIT)   // 128 j per split
#define NTT (JSPL/16)      // 8 j-steps of 16 rows
#define NPH (NTT/4)        // 2 phases of 4 steps (64 rows)
#define PITCH 272          // 256B row + 16B pad (bank decorrelation)

typedef __attribute__((ext_vector_type(8))) short short8v;
typedef __attribute__((ext_vector_type(4))) float float4v;

#define SQS 3.798282f                 // sqrt((1/TAU)/ln2): fold scale into bf16 z
#define LN2F 0.69314718055994531f

#define EXP2(x) __builtin_amdgcn_exp2f(x)
#define LOG2(x) __builtin_amdgcn_logf(x)

// ---- workspace layout (bytes) ----
#define WS_ZBF   0u          // bf16 z (pre-scaled): 2097152
#define WS_CNTP  2097152u    // cntpart[8][128] int = 4096 (plain stores, no zeroing)
#define WS_ACC   2101248u    // accf, accn, ticket, pad = 16 (zeroed by k_prep)
#define WS_LAB   2101264u    // labu8[8192] = 8192
#define WS_PM    2109456u    // partM[64][8192] f32 = 2097152
#define WS_PL    4206608u    // partL[64][8192] f32 = 2097152
#define WS_PP    6303760u    // partPS[64][8192] f32 = 2097152 (end 8400912)

__device__ __forceinline__ unsigned short f2bf(float x){
  unsigned u = __float_as_uint(x);
  u += 0x7fffu + ((u>>16)&1u);      // RNE
  return (unsigned short)(u>>16);
}

// blocks 0..511: convert+prescale z->bf16; 512..519: labels->u8 + histogram slab.
// block 512 thread 0 also zeroes acc/ticket (read only by later kernels).
__global__ __launch_bounds__(256) void k_prep(const float* __restrict__ z,
                                              const int* __restrict__ labels,
                                              unsigned short* __restrict__ zbf,
                                              unsigned* __restrict__ labu8,
                                              int* __restrict__ cntpart,
                                              float* accf, int* accn, int* ticket){
  const int bid = blockIdx.x, t = threadIdx.x;
  if (bid < 512){
    int idx = bid*256 + t;
    const float4* zi = (const float4*)z;
    float4 a = zi[idx*2], b = zi[idx*2+1];
    uint4 o;
    o.x = (unsigned)f2bf(a.x*SQS) | ((unsigned)f2bf(a.y*SQS)<<16);
    o.y = (unsigned)f2bf(a.z*SQS) | ((unsigned)f2bf(a.w*SQS)<<16);
    o.z = (unsigned)f2bf(b.x*SQS) | ((unsigned)f2bf(b.y*SQS)<<16);
    o.w = (unsigned)f2bf(b.z*SQS) | ((unsigned)f2bf(b.w*SQS)<<16);
    ((uint4*)zbf)[idx] = o;
    return;
  }
  __shared__ int hist[128];
  const int cb = bid - 512;              // 8 blocks x 1024 labels
  if (t < 128) hist[t] = 0;
  if (bid == 512 && t == 0){ accf[0] = 0.f; accn[0] = 0; ticket[0] = 0; }
  __syncthreads();
  {  // pack 4 labels -> u32, and histogram
    int i = cb*1024 + t*4;
    int4 l4 = *(const int4*)(labels + i);
    labu8[cb*256 + t] = (unsigned)l4.x | ((unsigned)l4.y<<8)
                      | ((unsigned)l4.z<<16) | ((unsigned)l4.w<<24);
    atomicAdd(&hist[l4.x], 1); atomicAdd(&hist[l4.y], 1);
    atomicAdd(&hist[l4.z], 1); atomicAdd(&hist[l4.w], 1);
  }
  __syncthreads();
  if (t < 128) cntpart[cb*128 + t] = hist[t];   // plain store, no global zero
}

// 2048 blocks x 256 (4 waves) -> 32 waves/CU nominal. Block shares one split;
// A-tile staged once per block into LDS, 64-row double-buffered phases.
__global__ __launch_bounds__(256) void k_lse(const unsigned short* __restrict__ zbf,
                                             const int* __restrict__ labels,
                                             const unsigned* __restrict__ labu8,
                                             float* __restrict__ partM,
                                             float* __restrict__ partL,
                                             float* __restrict__ partPS){
  __shared__ __align__(16) unsigned char atile[2][64*PITCH];  // 2 x 17 KB
  __shared__ unsigned ldslab[JSPL/4];      // 32 words = this split's 128 labels
  const int t = threadIdx.x, wv = t>>6, lane = t&63;
  const int bid = blockIdx.x;
  const int xcd = bid & 7, chunk = bid >> 3;         // chunk 0..255
  const int split = (xcd<<3) | (chunk & 7);          // XCD owns 8 j-windows
  const int ablk  = ((chunk>>3)<<2) | wv;            // 0..127
  const int awave = ablk*64;
  const int j0 = split*JSPL;
  const int lg = lane>>4, ln = lane&15;
  const bool DIAG = ((awave >> 7) == split);

  if (t < JSPL/4) ldslab[t] = labu8[(j0>>2) + t];

  // anchor B-fragments: B[k][n]; lane: n=ln, k=kk*32+lg*8+e
  short8v bf[4][4];
  int labA[4];
  #pragma unroll
  for (int ss = 0; ss < 4; ss++){
    const unsigned short* zr = zbf + (size_t)(awave + ss*16 + ln)*WD;
    #pragma unroll
    for (int kk = 0; kk < 4; kk++)
      bf[ss][kk] = *(const short8v*)(zr + kk*32 + lg*8);
    labA[ss] = labels[awave + ss*16 + ln];
  }

  float m[4], l[4], ps[4];
  #pragma unroll
  for (int ss = 0; ss < 4; ss++){ m[ss] = -INFINITY; l[ss] = 0.f; ps[ss] = 0.f; }

  // staging: thread t handles row srow0+16q, 16B chunk sck (q=0..3)
  const int srow0 = t>>4, sck = t&15;
  const unsigned short* sb = zbf + (size_t)(j0 + srow0)*WD + sck*8;
  const unsigned swbase = srow0*PITCH + sck*16;

  // prologue: stage phase 0 into buf 0
  {
    uint4 s0 = *(const uint4*)(sb + (size_t)( 0)*WD);
    uint4 s1 = *(const uint4*)(sb + (size_t)(16)*WD);
    uint4 s2 = *(const uint4*)(sb + (size_t)(32)*WD);
    uint4 s3 = *(const uint4*)(sb + (size_t)(48)*WD);
    *(uint4*)&atile[0][swbase +  0*PITCH] = s0;
    *(uint4*)&atile[0][swbase + 16*PITCH] = s1;
    *(uint4*)&atile[0][swbase + 32*PITCH] = s2;
    *(uint4*)&atile[0][swbase + 48*PITCH] = s3;
  }
  __syncthreads();

  for (int ph = 0; ph < NPH; ph++){
    const int cur = ph & 1;
    // T14: issue next phase's global loads NOW; they drain during compute
    uint4 nx0, nx1, nx2, nx3;
    const bool have = (ph+1 < NPH);
    if (have){
      const unsigned short* nb = sb + (size_t)((ph+1)*64)*WD;
      nx0 = *(const uint4*)(nb + (size_t)( 0)*WD);
      nx1 = *(const uint4*)(nb + (size_t)(16)*WD);
      nx2 = *(const uint4*)(nb + (size_t)(32)*WD);
      nx3 = *(const uint4*)(nb + (size_t)(48)*WD);
    }
    #pragma unroll
    for (int s = 0; s < 4; s++){
      const int tt = ph*4 + s;
      const int jb = j0 + tt*16;
      const unsigned lw = ldslab[tt*4 + lg];
      const int b0 = (int)(lw&255u),       b1 = (int)((lw>>8)&255u);
      const int b2 = (int)((lw>>16)&255u), b3 = (int)(lw>>24);
      const int rl = s*16 + ln;
      const unsigned rbase = rl*PITCH + lg*16;
      short8v af0 = *(const short8v*)&atile[cur][rbase +   0];
      short8v af1 = *(const short8v*)&atile[cur][rbase +  64];
      short8v af2 = *(const short8v*)&atile[cur][rbase + 128];
      short8v af3 = *(const short8v*)&atile[cur][rbase + 192];
      #pragma unroll
      for (int ss = 0; ss < 4; ss++){
        float4v acc = {0.f,0.f,0.f,0.f};
        acc = __builtin_amdgcn_mfma_f32_16x16x32_bf16(af0, bf[ss][0], acc, 0,0,0);
        acc = __builtin_amdgcn_mfma_f32_16x16x32_bf16(af1, bf[ss][1], acc, 0,0,0);
        acc = __builtin_amdgcn_mfma_f32_16x16x32_bf16(af2, bf[ss][2], acc, 0,0,0);
        acc = __builtin_amdgcn_mfma_f32_16x16x32_bf16(af3, bf[ss][3], acc, 0,0,0);
        float v0 = acc[0], v1 = acc[1], v2 = acc[2], v3 = acc[3];
        ps[ss] += ((b0==labA[ss]) ? v0 : 0.f) + ((b1==labA[ss]) ? v1 : 0.f)
                + ((b2==labA[ss]) ? v2 : 0.f) + ((b3==labA[ss]) ? v3 : 0.f);
        if (DIAG && jb == awave + ss*16){   // wave-uniform; self always matches
          const int r0 = lg*4;
          if (r0+0 == ln){ ps[ss] -= v0; v0 = -INFINITY; }
          if (r0+1 == ln){ ps[ss] -= v1; v1 = -INFINITY; }
          if (r0+2 == ln){ ps[ss] -= v2; v2 = -INFINITY; }
          if (r0+3 == ln){ ps[ss] -= v3; v3 = -INFINITY; }
        }
        float tmax = fmaxf(fmaxf(v0,v1), fmaxf(v2,v3));
        float mn = fmaxf(m[ss], tmax);
        l[ss] = l[ss]*EXP2(m[ss]-mn)
              + ((EXP2(v0-mn) + EXP2(v1-mn)) + (EXP2(v2-mn) + EXP2(v3-mn)));
        m[ss] = mn;
      }
    }
    if (have){
      *(uint4*)&atile[cur^1][swbase +  0*PITCH] = nx0;
      *(uint4*)&atile[cur^1][swbase + 16*PITCH] = nx1;
      *(uint4*)&atile[cur^1][swbase + 32*PITCH] = nx2;
      *(uint4*)&atile[cur^1][swbase + 48*PITCH] = nx3;
    }
    __syncthreads();
  }

  // combine lanes {x^16, x^32} (same anchor, different j-row groups)
  #pragma unroll
  for (int ss = 0; ss < 4; ss++){
    float mm = m[ss], ll = l[ss], pp = ps[ss];
    #pragma unroll
    for (int off = 16; off < 64; off <<= 1){
      float mo = __shfl_xor(mm, off);
      float lo = __shfl_xor(ll, off);
      float M = fmaxf(mm, mo);
      ll = ll*EXP2(mm-M) + lo*EXP2(mo-M);
      mm = M;
      pp += __shfl_xor(pp, off);
    }
    if (lane < 16){
      size_t o = (size_t)split*WB + awave + ss*16 + lane;
      partM[o] = mm; partL[o] = ll; partPS[o] = pp;
    }
  }
}

// 32 blocks x 256 threads: one anchor per thread.
__global__ __launch_bounds__(256) void k_final(const int* __restrict__ labels,
                                               const int* __restrict__ cntpart,
                                               const float* __restrict__ partM,
                                               const float* __restrict__ partL,
                                               const float* __restrict__ partPS,
                                               float* accf, int* accn, int* ticket,
                                               float* __restrict__ out){
  const int t = threadIdx.x;
  const int a = blockIdx.x*256 + t;
  float mm = -INFINITY;
  #pragma unroll 8
  for (int sp = 0; sp < NSPLIT; sp++)
    mm = fmaxf(mm, partM[(size_t)sp*WB + a]);
  float ll = 0.f, pp = 0.f;
  #pragma unroll 8
  for (int sp = 0; sp < NSPLIT; sp++){
    ll = fmaf(partL[(size_t)sp*WB + a], EXP2(partM[(size_t)sp*WB + a] - mm), ll);
    pp += partPS[(size_t)sp*WB + a];
  }
  float lse2 = mm + LOG2(ll);             // log2 units
  int lab = labels[a];
  int c = 0;
  #pragma unroll
  for (int b = 0; b < 8; b++) c += cntpart[b*128 + lab];
  int np = c - 1;
  float loss = 0.f, val = 0.f;
  if (np > 0){ loss = LN2F*(lse2 - pp/(float)np); val = 1.f; }
  #pragma unroll
  for (int off = 32; off > 0; off >>= 1){
    loss += __shfl_down(loss, off);
    val  += __shfl_down(val,  off);
  }
  __shared__ float sl[4], sv[4];
  int wv = t>>6, lane = t&63;
  if (lane == 0){ sl[wv] = loss; sv[wv] = val; }
  __syncthreads();
  if (t == 0){
    atomicAdd(accf, sl[0]+sl[1]+sl[2]+sl[3]);
    atomicAdd(accn, (int)(sv[0]+sv[1]+sv[2]+sv[3] + 0.5f));
    __threadfence();
    int tk = atomicAdd(ticket, 1);
    if (tk == 31){                         // last block finalizes
      float f = atomicAdd(accf, 0.f);
      int   n = atomicAdd(accn, 0);
      out[0] = f / (float)max(n, 1);
    }
  }
}

extern "C" void kernel_launch(void* const* d_in, const int* in_sizes, int n_in,
                              void* d_out, int out_size, void* d_ws, size_t ws_size,
                              hipStream_t stream){
  const float* z = (const float*)d_in[0];
  const int* labels = (const int*)d_in[1];
  char* ws = (char*)d_ws;
  unsigned short* zbf = (unsigned short*)(ws + WS_ZBF);
  int*      cntp   = (int*)(ws + WS_CNTP);
  float*    accf   = (float*)(ws + WS_ACC);
  int*      accn   = (int*)(ws + WS_ACC + 4);
  int*      ticket = (int*)(ws + WS_ACC + 8);
  unsigned* labu8  = (unsigned*)(ws + WS_LAB);
  float*    partM  = (float*)(ws + WS_PM);
  float*    partL  = (float*)(ws + WS_PL);
  float*    partPS = (float*)(ws + WS_PP);
  float* out = (float*)d_out;

  hipLaunchKernelGGL(k_prep,  dim3(520),  dim3(256), 0, stream,
                     z, labels, zbf, labu8, cntp, accf, accn, ticket);
  hipLaunchKernelGGL(k_lse,   dim3(2048), dim3(256), 0, stream,
                     zbf, labels, labu8, partM, partL, partPS);
  hipLaunchKernelGGL(k_final, dim3(32),   dim3(256), 0, stream,
                     labels, cntp, partM, partL, partPS, accf, accn, ticket, out);
}

// Round 18
// 62.021 us; speedup vs baseline: 1.0703x; 1.0703x over previous
//
#include <hip/hip_runtime.h>
#include <hip/hip_bf16.h>

#define WB 8192
#define WD 128
#define WC 100
#define NSPLIT 16
#define JSPL (WB/NSPLIT)   // 512 j per split
#define NTT (JSPL/16)      // 32 j-steps of 16 rows
#define NPH (NTT/4)        // 8 phases of 4 steps (64 rows)
#define PITCH 272          // 256B row + 16B pad (bank decorrelation)

typedef __attribute__((ext_vector_type(8))) short short8v;
typedef __attribute__((ext_vector_type(4))) float float4v;

#define SQS 3.798282f                 // sqrt((1/TAU)/ln2): fold scale into bf16 z
#define LN2F 0.69314718055994531f

#define EXP2(x) __builtin_amdgcn_exp2f(x)
#define LOG2(x) __builtin_amdgcn_logf(x)

// ---- workspace layout (bytes) ----
#define WS_ZBF   0u          // bf16 z (pre-scaled): 2097152
#define WS_CNTP  2097152u    // cntpart[8][128] int = 4096 (plain stores)
#define WS_ACC   2101248u    // accf, accn, ticket, pad = 16 (zeroed by k_prep)
#define WS_LAB   2101264u    // labu8[8192] = 8192
#define WS_RMAX  2109456u    // rmax[8192] u32 = 32768 (init by k_prep)
#define WS_PL    2142224u    // partL[16][8192] f32 = 524288
#define WS_PP    2666512u    // partPS[16][8192] f32 = 524288 (end 3190800)

__device__ __forceinline__ unsigned short f2bf(float x){
  unsigned u = __float_as_uint(x);
  u += 0x7fffu + ((u>>16)&1u);      // RNE
  return (unsigned short)(u>>16);
}
// order-preserving float<->uint key for atomicMax (key 0 < any real key)
__device__ __forceinline__ unsigned fkey(float x){
  unsigned u = __float_as_uint(x);
  return (u>>31) ? ~u : (u | 0x80000000u);
}
__device__ __forceinline__ float fkeyinv(unsigned k){
  return (k>>31) ? __uint_as_float(k & 0x7FFFFFFFu) : __uint_as_float(~k);
}

// blocks 0..511: convert+prescale z->bf16; 512..519: labels->u8 + hist + rmax init
__global__ __launch_bounds__(256) void k_prep(const float* __restrict__ z,
                                              const int* __restrict__ labels,
                                              unsigned short* __restrict__ zbf,
                                              unsigned* __restrict__ labu8,
                                              int* __restrict__ cntpart,
                                              unsigned* __restrict__ rmax,
                                              float* accf, int* accn, int* ticket){
  const int bid = blockIdx.x, t = threadIdx.x;
  if (bid < 512){
    int idx = bid*256 + t;
    const float4* zi = (const float4*)z;
    float4 a = zi[idx*2], b = zi[idx*2+1];
    uint4 o;
    o.x = (unsigned)f2bf(a.x*SQS) | ((unsigned)f2bf(a.y*SQS)<<16);
    o.y = (unsigned)f2bf(a.z*SQS) | ((unsigned)f2bf(a.w*SQS)<<16);
    o.z = (unsigned)f2bf(b.x*SQS) | ((unsigned)f2bf(b.y*SQS)<<16);
    o.w = (unsigned)f2bf(b.z*SQS) | ((unsigned)f2bf(b.w*SQS)<<16);
    ((uint4*)zbf)[idx] = o;
    return;
  }
  __shared__ int hist[128];
  const int cb = bid - 512;              // 8 blocks x 1024 labels
  if (t < 128) hist[t] = 0;
  if (bid == 512 && t == 0){ accf[0] = 0.f; accn[0] = 0; ticket[0] = 0; }
  __syncthreads();
  for (int i = t; i < 1024; i += 256) rmax[cb*1024 + i] = 0u;
  {  // pack 4 labels -> u32, and histogram
    int i = cb*1024 + t*4;
    int4 l4 = *(const int4*)(labels + i);
    labu8[cb*256 + t] = (unsigned)l4.x | ((unsigned)l4.y<<8)
                      | ((unsigned)l4.z<<16) | ((unsigned)l4.w<<24);
    atomicAdd(&hist[l4.x], 1); atomicAdd(&hist[l4.y], 1);
    atomicAdd(&hist[l4.z], 1); atomicAdd(&hist[l4.w], 1);
  }
  __syncthreads();
  if (t < 128) cntpart[cb*128 + t] = hist[t];
}

// PASS A: diag-masked row max only. 512 blocks x 256; LDS-staged A-tiles.
__global__ __launch_bounds__(256) void k_max(const unsigned short* __restrict__ zbf,
                                             unsigned* __restrict__ rmax){
  __shared__ __align__(16) unsigned char atile[2][64*PITCH];  // 2 x 17 KB
  const int t = threadIdx.x, wv = t>>6, lane = t&63;
  const int bid = blockIdx.x;
  const int xcd = bid & 7, chunk = bid >> 3;
  const int split = (xcd<<1) | (chunk & 1);
  const int ablk  = ((chunk>>1)<<2) | wv;
  const int awave = ablk*64;
  const int j0 = split*JSPL;
  const int lg = lane>>4, ln = lane&15;
  const bool DIAG = ((awave >> 9) == split);

  short8v bf[4][4];
  #pragma unroll
  for (int ss = 0; ss < 4; ss++){
    const unsigned short* zr = zbf + (size_t)(awave + ss*16 + ln)*WD;
    #pragma unroll
    for (int kk = 0; kk < 4; kk++)
      bf[ss][kk] = *(const short8v*)(zr + kk*32 + lg*8);
  }
  float m0[4], m1[4];
  #pragma unroll
  for (int ss = 0; ss < 4; ss++){ m0[ss] = -INFINITY; m1[ss] = -INFINITY; }

  const int srow0 = t>>4, sck = t&15;
  const unsigned short* sb = zbf + (size_t)(j0 + srow0)*WD + sck*8;
  const unsigned swbase = srow0*PITCH + sck*16;
  {
    uint4 s0 = *(const uint4*)(sb + (size_t)( 0)*WD);
    uint4 s1 = *(const uint4*)(sb + (size_t)(16)*WD);
    uint4 s2 = *(const uint4*)(sb + (size_t)(32)*WD);
    uint4 s3 = *(const uint4*)(sb + (size_t)(48)*WD);
    *(uint4*)&atile[0][swbase +  0*PITCH] = s0;
    *(uint4*)&atile[0][swbase + 16*PITCH] = s1;
    *(uint4*)&atile[0][swbase + 32*PITCH] = s2;
    *(uint4*)&atile[0][swbase + 48*PITCH] = s3;
  }
  __syncthreads();

  for (int ph = 0; ph < NPH; ph++){
    const int cur = ph & 1;
    uint4 nx0, nx1, nx2, nx3;
    const bool have = (ph+1 < NPH);
    if (have){
      const unsigned short* nb = sb + (size_t)((ph+1)*64)*WD;
      nx0 = *(const uint4*)(nb + (size_t)( 0)*WD);
      nx1 = *(const uint4*)(nb + (size_t)(16)*WD);
      nx2 = *(const uint4*)(nb + (size_t)(32)*WD);
      nx3 = *(const uint4*)(nb + (size_t)(48)*WD);
    }
    #pragma unroll
    for (int s = 0; s < 4; s++){
      const int tt = ph*4 + s;
      const int jb = j0 + tt*16;
      const int rl = s*16 + ln;
      const unsigned rbase = rl*PITCH + lg*16;
      short8v af0 = *(const short8v*)&atile[cur][rbase +   0];
      short8v af1 = *(const short8v*)&atile[cur][rbase +  64];
      short8v af2 = *(const short8v*)&atile[cur][rbase + 128];
      short8v af3 = *(const short8v*)&atile[cur][rbase + 192];
      #pragma unroll
      for (int ss = 0; ss < 4; ss++){
        float4v acc = {0.f,0.f,0.f,0.f};
        acc = __builtin_amdgcn_mfma_f32_16x16x32_bf16(af0, bf[ss][0], acc, 0,0,0);
        acc = __builtin_amdgcn_mfma_f32_16x16x32_bf16(af1, bf[ss][1], acc, 0,0,0);
        acc = __builtin_amdgcn_mfma_f32_16x16x32_bf16(af2, bf[ss][2], acc, 0,0,0);
        acc = __builtin_amdgcn_mfma_f32_16x16x32_bf16(af3, bf[ss][3], acc, 0,0,0);
        float v0 = acc[0], v1 = acc[1], v2 = acc[2], v3 = acc[3];
        if (DIAG && jb == awave + ss*16){
          const int r0 = lg*4;
          if (r0+0 == ln) v0 = -INFINITY;
          if (r0+1 == ln) v1 = -INFINITY;
          if (r0+2 == ln) v2 = -INFINITY;
          if (r0+3 == ln) v3 = -INFINITY;
        }
        m0[ss] = fmaxf(m0[ss], fmaxf(v0,v1));   // 2 independent stripes
        m1[ss] = fmaxf(m1[ss], fmaxf(v2,v3));
      }
    }
    if (have){
      *(uint4*)&atile[cur^1][swbase +  0*PITCH] = nx0;
      *(uint4*)&atile[cur^1][swbase + 16*PITCH] = nx1;
      *(uint4*)&atile[cur^1][swbase + 32*PITCH] = nx2;
      *(uint4*)&atile[cur^1][swbase + 48*PITCH] = nx3;
    }
    __syncthreads();
  }

  #pragma unroll
  for (int ss = 0; ss < 4; ss++){
    float mm = fmaxf(m0[ss], m1[ss]);
    mm = fmaxf(mm, __shfl_xor(mm, 16));
    mm = fmaxf(mm, __shfl_xor(mm, 32));
    if (lane < 16) atomicMax(&rmax[awave + ss*16 + lane], fkey(mm));
  }
}

// PASS B: fixed-max exp-sum + fused pos-sum. 512 blocks x 256; LDS-staged.
__global__ __launch_bounds__(256) void k_sum(const unsigned short* __restrict__ zbf,
                                             const int* __restrict__ labels,
                                             const unsigned* __restrict__ labu8,
                                             const unsigned* __restrict__ rmax,
                                             float* __restrict__ partL,
                                             float* __restrict__ partPS){
  __shared__ __align__(16) unsigned char atile[2][64*PITCH];  // 2 x 17 KB
  __shared__ unsigned ldslab[JSPL/4];
  const int t = threadIdx.x, wv = t>>6, lane = t&63;
  const int bid = blockIdx.x;
  const int xcd = bid & 7, chunk = bid >> 3;
  const int split = (xcd<<1) | (chunk & 1);
  const int ablk  = ((chunk>>1)<<2) | wv;
  const int awave = ablk*64;
  const int j0 = split*JSPL;
  const int lg = lane>>4, ln = lane&15;
  const bool DIAG = ((awave >> 9) == split);

  if (t < JSPL/4) ldslab[t] = labu8[(j0>>2) + t];

  short8v bf[4][4];
  int labA[4];
  float mf[4];
  #pragma unroll
  for (int ss = 0; ss < 4; ss++){
    const unsigned short* zr = zbf + (size_t)(awave + ss*16 + ln)*WD;
    #pragma unroll
    for (int kk = 0; kk < 4; kk++)
      bf[ss][kk] = *(const short8v*)(zr + kk*32 + lg*8);
    labA[ss] = labels[awave + ss*16 + ln];
    mf[ss] = fkeyinv(rmax[awave + ss*16 + ln]);
  }
  float l0[4], l1[4], ps[4];
  #pragma unroll
  for (int ss = 0; ss < 4; ss++){ l0[ss] = 0.f; l1[ss] = 0.f; ps[ss] = 0.f; }

  const int srow0 = t>>4, sck = t&15;
  const unsigned short* sb = zbf + (size_t)(j0 + srow0)*WD + sck*8;
  const unsigned swbase = srow0*PITCH + sck*16;
  {
    uint4 s0 = *(const uint4*)(sb + (size_t)( 0)*WD);
    uint4 s1 = *(const uint4*)(sb + (size_t)(16)*WD);
    uint4 s2 = *(const uint4*)(sb + (size_t)(32)*WD);
    uint4 s3 = *(const uint4*)(sb + (size_t)(48)*WD);
    *(uint4*)&atile[0][swbase +  0*PITCH] = s0;
    *(uint4*)&atile[0][swbase + 16*PITCH] = s1;
    *(uint4*)&atile[0][swbase + 32*PITCH] = s2;
    *(uint4*)&atile[0][swbase + 48*PITCH] = s3;
  }
  __syncthreads();

  for (int ph = 0; ph < NPH; ph++){
    const int cur = ph & 1;
    uint4 nx0, nx1, nx2, nx3;
    const bool have = (ph+1 < NPH);
    if (have){
      const unsigned short* nb = sb + (size_t)((ph+1)*64)*WD;
      nx0 = *(const uint4*)(nb + (size_t)( 0)*WD);
      nx1 = *(const uint4*)(nb + (size_t)(16)*WD);
      nx2 = *(const uint4*)(nb + (size_t)(32)*WD);
      nx3 = *(const uint4*)(nb + (size_t)(48)*WD);
    }
    #pragma unroll
    for (int s = 0; s < 4; s++){
      const int tt = ph*4 + s;
      const int jb = j0 + tt*16;
      const unsigned lw = ldslab[tt*4 + lg];
      const int b0 = (int)(lw&255u),       b1 = (int)((lw>>8)&255u);
      const int b2 = (int)((lw>>16)&255u), b3 = (int)(lw>>24);
      const int rl = s*16 + ln;
      const unsigned rbase = rl*PITCH + lg*16;
      short8v af0 = *(const short8v*)&atile[cur][rbase +   0];
      short8v af1 = *(const short8v*)&atile[cur][rbase +  64];
      short8v af2 = *(const short8v*)&atile[cur][rbase + 128];
      short8v af3 = *(const short8v*)&atile[cur][rbase + 192];
      #pragma unroll
      for (int ss = 0; ss < 4; ss++){
        float4v acc = {0.f,0.f,0.f,0.f};
        acc = __builtin_amdgcn_mfma_f32_16x16x32_bf16(af0, bf[ss][0], acc, 0,0,0);
        acc = __builtin_amdgcn_mfma_f32_16x16x32_bf16(af1, bf[ss][1], acc, 0,0,0);
        acc = __builtin_amdgcn_mfma_f32_16x16x32_bf16(af2, bf[ss][2], acc, 0,0,0);
        acc = __builtin_amdgcn_mfma_f32_16x16x32_bf16(af3, bf[ss][3], acc, 0,0,0);
        float v0 = acc[0], v1 = acc[1], v2 = acc[2], v3 = acc[3];
        ps[ss] += ((b0==labA[ss]) ? v0 : 0.f) + ((b1==labA[ss]) ? v1 : 0.f)
                + ((b2==labA[ss]) ? v2 : 0.f) + ((b3==labA[ss]) ? v3 : 0.f);
        if (DIAG && jb == awave + ss*16){
          const int r0 = lg*4;
          if (r0+0 == ln){ ps[ss] -= v0; v0 = -INFINITY; }
          if (r0+1 == ln){ ps[ss] -= v1; v1 = -INFINITY; }
          if (r0+2 == ln){ ps[ss] -= v2; v2 = -INFINITY; }
          if (r0+3 == ln){ ps[ss] -= v3; v3 = -INFINITY; }
        }
        // fixed max: no rescale, no chain; 2 independent stripes
        l0[ss] += EXP2(v0-mf[ss]) + EXP2(v1-mf[ss]);
        l1[ss] += EXP2(v2-mf[ss]) + EXP2(v3-mf[ss]);
      }
    }
    if (have){
      *(uint4*)&atile[cur^1][swbase +  0*PITCH] = nx0;
      *(uint4*)&atile[cur^1][swbase + 16*PITCH] = nx1;
      *(uint4*)&atile[cur^1][swbase + 32*PITCH] = nx2;
      *(uint4*)&atile[cur^1][swbase + 48*PITCH] = nx3;
    }
    __syncthreads();
  }

  #pragma unroll
  for (int ss = 0; ss < 4; ss++){
    float ll = l0[ss] + l1[ss], pp = ps[ss];
    ll += __shfl_xor(ll, 16); pp += __shfl_xor(pp, 16);
    ll += __shfl_xor(ll, 32); pp += __shfl_xor(pp, 32);
    if (lane < 16){
      size_t o = (size_t)split*WB + awave + ss*16 + lane;
      partL[o] = ll; partPS[o] = pp;
    }
  }
}

// 32 blocks x 256 threads: one anchor per thread. No per-split rescale needed.
__global__ __launch_bounds__(256) void k_final(const int* __restrict__ labels,
                                               const int* __restrict__ cntpart,
                                               const unsigned* __restrict__ rmax,
                                               const float* __restrict__ partL,
                                               const float* __restrict__ partPS,
                                               float* accf, int* accn, int* ticket,
                                               float* __restrict__ out){
  const int t = threadIdx.x;
  const int a = blockIdx.x*256 + t;
  float ll = 0.f, pp = 0.f;
  #pragma unroll 8
  for (int sp = 0; sp < NSPLIT; sp++){
    ll += partL[(size_t)sp*WB + a];
    pp += partPS[(size_t)sp*WB + a];
  }
  float lse2 = fkeyinv(rmax[a]) + LOG2(ll);   // log2 units
  int lab = labels[a];
  int c = 0;
  #pragma unroll
  for (int b = 0; b < 8; b++) c += cntpart[b*128 + lab];
  int np = c - 1;
  float loss = 0.f, val = 0.f;
  if (np > 0){ loss = LN2F*(lse2 - pp/(float)np); val = 1.f; }
  #pragma unroll
  for (int off = 32; off > 0; off >>= 1){
    loss += __shfl_down(loss, off);
    val  += __shfl_down(val,  off);
  }
  __shared__ float sl[4], sv[4];
  int wv = t>>6, lane = t&63;
  if (lane == 0){ sl[wv] = loss; sv[wv] = val; }
  __syncthreads();
  if (t == 0){
    atomicAdd(accf, sl[0]+sl[1]+sl[2]+sl[3]);
    atomicAdd(accn, (int)(sv[0]+sv[1]+sv[2]+sv[3] + 0.5f));
    __threadfence();
    int tk = atomicAdd(ticket, 1);
    if (tk == 31){
      float f = atomicAdd(accf, 0.f);
      int   n = atomicAdd(accn, 0);
      out[0] = f / (float)max(n, 1);
    }
  }
}

extern "C" void kernel_launch(void* const* d_in, const int* in_sizes, int n_in,
                              void* d_out, int out_size, void* d_ws, size_t ws_size,
                              hipStream_t stream){
  const float* z = (const float*)d_in[0];
  const int* labels = (const int*)d_in[1];
  char* ws = (char*)d_ws;
  unsigned short* zbf = (unsigned short*)(ws + WS_ZBF);
  int*      cntp   = (int*)(ws + WS_CNTP);
  float*    accf   = (float*)(ws + WS_ACC);
  int*      accn   = (int*)(ws + WS_ACC + 4);
  int*      ticket = (int*)(ws + WS_ACC + 8);
  unsigned* labu8  = (unsigned*)(ws + WS_LAB);
  unsigned* rmax   = (unsigned*)(ws + WS_RMAX);
  float*    partL  = (float*)(ws + WS_PL);
  float*    partPS = (float*)(ws + WS_PP);
  float* out = (float*)d_out;

  hipLaunchKernelGGL(k_prep,  dim3(520), dim3(256), 0, stream,
                     z, labels, zbf, labu8, cntp, rmax, accf, accn, ticket);
  hipLaunchKernelGGL(k_max,   dim3(512), dim3(256), 0, stream, zbf, rmax);
  hipLaunchKernelGGL(k_sum,   dim3(512), dim3(256), 0, stream,
                     zbf, labels, labu8, rmax, partL, partPS);
  hipLaunchKernelGGL(k_final, dim3(32),  dim3(256), 0, stream,
                     labels, cntp, rmax, partL, partPS, accf, accn, ticket, out);
}

// Round 19
// 49.522 us; speedup vs baseline: 1.3405x; 1.2524x over previous
//
#include <hip/hip_runtime.h>
#include <hip/hip_bf16.h>

#define WB 8192
#define WD 128
#define WC 100
#define NSPLIT 16
#define JSPL (WB/NSPLIT)   // 512 j per split
#define NTT (JSPL/16)      // 32 j-steps of 16 rows
#define NPH (NTT/4)        // 8 phases of 4 steps (64 rows)
#define PITCH 272          // 256B row + 16B pad (bank decorrelation)

typedef __attribute__((ext_vector_type(8))) short short8v;
typedef __attribute__((ext_vector_type(4))) float float4v;

#define SQS 3.798282f                 // sqrt((1/TAU)/ln2): fold scale into bf16 z
#define LN2F 0.69314718055994531f

#define EXP2(x) __builtin_amdgcn_exp2f(x)
#define LOG2(x) __builtin_amdgcn_logf(x)

// ---- workspace layout (bytes) ----
#define WS_ZBF   0u          // bf16 z (pre-scaled): 2097152
#define WS_CNTP  2097152u    // cntpart[8][128] int = 4096 (plain stores, no zeroing)
#define WS_ACC   2101248u    // accf, accn, ticket, pad = 16 (zeroed by k_prep)
#define WS_LAB   2101264u    // labu8[8192] = 8192
#define WS_PM    2109456u    // partM[16][8192] f32 = 524288
#define WS_PL    2633744u    // partL[16][8192] f32 = 524288
#define WS_PP    3158032u    // partPS[16][8192] f32 = 524288 (end 3682320)

__device__ __forceinline__ unsigned short f2bf(float x){
  unsigned u = __float_as_uint(x);
  u += 0x7fffu + ((u>>16)&1u);      // RNE
  return (unsigned short)(u>>16);
}

// blocks 0..511: convert+prescale z->bf16; 512..519: labels->u8 + histogram slab.
__global__ __launch_bounds__(256) void k_prep(const float* __restrict__ z,
                                              const int* __restrict__ labels,
                                              unsigned short* __restrict__ zbf,
                                              unsigned* __restrict__ labu8,
                                              int* __restrict__ cntpart,
                                              float* accf, int* accn, int* ticket){
  const int bid = blockIdx.x, t = threadIdx.x;
  if (bid < 512){
    int idx = bid*256 + t;
    const float4* zi = (const float4*)z;
    float4 a = zi[idx*2], b = zi[idx*2+1];
    uint4 o;
    o.x = (unsigned)f2bf(a.x*SQS) | ((unsigned)f2bf(a.y*SQS)<<16);
    o.y = (unsigned)f2bf(a.z*SQS) | ((unsigned)f2bf(a.w*SQS)<<16);
    o.z = (unsigned)f2bf(b.x*SQS) | ((unsigned)f2bf(b.y*SQS)<<16);
    o.w = (unsigned)f2bf(b.z*SQS) | ((unsigned)f2bf(b.w*SQS)<<16);
    ((uint4*)zbf)[idx] = o;
    return;
  }
  __shared__ int hist[128];
  const int cb = bid - 512;              // 8 blocks x 1024 labels
  if (t < 128) hist[t] = 0;
  if (bid == 512 && t == 0){ accf[0] = 0.f; accn[0] = 0; ticket[0] = 0; }
  __syncthreads();
  {  // pack 4 labels -> u32, and histogram
    int i = cb*1024 + t*4;
    int4 l4 = *(const int4*)(labels + i);
    labu8[cb*256 + t] = (unsigned)l4.x | ((unsigned)l4.y<<8)
                      | ((unsigned)l4.z<<16) | ((unsigned)l4.w<<24);
    atomicAdd(&hist[l4.x], 1); atomicAdd(&hist[l4.y], 1);
    atomicAdd(&hist[l4.z], 1); atomicAdd(&hist[l4.w], 1);
  }
  __syncthreads();
  if (t < 128) cntpart[cb*128 + t] = hist[t];   // plain store, no global zero
}

// 1024 blocks x 256 (4 waves, 32 anchors each -> 128 anchors/block).
// A-tile staged once per block into LDS, 64-row double-buffered phases.
// VGPR target ~95 (bf halved) -> 5 waves/SIMD cap; 4 blocks/CU launched.
__global__ __launch_bounds__(256) void k_lse(const unsigned short* __restrict__ zbf,
                                             const int* __restrict__ labels,
                                             const unsigned* __restrict__ labu8,
                                             float* __restrict__ partM,
                                             float* __restrict__ partL,
                                             float* __restrict__ partPS){
  __shared__ __align__(16) unsigned char atile[2][64*PITCH];  // 2 x 17 KB
  __shared__ unsigned ldslab[JSPL/4];      // 128 words = this split's 512 labels
  const int t = threadIdx.x, wv = t>>6, lane = t&63;
  const int bid = blockIdx.x;
  const int xcd = bid & 7, chunk = bid >> 3;         // chunk 0..127
  const int split = (xcd<<1) | (chunk & 1);          // XCD owns 2 j-windows
  const int ablk  = chunk >> 1;                      // 0..63 (128 anchors each)
  const int awave = ablk*128 + wv*32;                // wave owns 32 anchors
  const int j0 = split*JSPL;
  const int lg = lane>>4, ln = lane&15;
  const bool DIAG = ((awave >> 9) == split);

  if (t < JSPL/4) ldslab[t] = labu8[(j0>>2) + t];

  // anchor B-fragments: B[k][n]; lane: n=ln, k=kk*32+lg*8+e
  short8v bf[2][4];
  int labA[2];
  #pragma unroll
  for (int ss = 0; ss < 2; ss++){
    const unsigned short* zr = zbf + (size_t)(awave + ss*16 + ln)*WD;
    #pragma unroll
    for (int kk = 0; kk < 4; kk++)
      bf[ss][kk] = *(const short8v*)(zr + kk*32 + lg*8);
    labA[ss] = labels[awave + ss*16 + ln];
  }

  float m[2], l[2], ps[2];
  #pragma unroll
  for (int ss = 0; ss < 2; ss++){ m[ss] = -INFINITY; l[ss] = 0.f; ps[ss] = 0.f; }

  // staging: thread t handles row srow0+16q, 16B chunk sck (q=0..3)
  const int srow0 = t>>4, sck = t&15;
  const unsigned short* sb = zbf + (size_t)(j0 + srow0)*WD + sck*8;
  const unsigned swbase = srow0*PITCH + sck*16;

  // prologue: stage phase 0 into buf 0
  {
    uint4 s0 = *(const uint4*)(sb + (size_t)( 0)*WD);
    uint4 s1 = *(const uint4*)(sb + (size_t)(16)*WD);
    uint4 s2 = *(const uint4*)(sb + (size_t)(32)*WD);
    uint4 s3 = *(const uint4*)(sb + (size_t)(48)*WD);
    *(uint4*)&atile[0][swbase +  0*PITCH] = s0;
    *(uint4*)&atile[0][swbase + 16*PITCH] = s1;
    *(uint4*)&atile[0][swbase + 32*PITCH] = s2;
    *(uint4*)&atile[0][swbase + 48*PITCH] = s3;
  }
  __syncthreads();

  for (int ph = 0; ph < NPH; ph++){
    const int cur = ph & 1;
    // T14: issue next phase's global loads NOW; they drain during compute
    uint4 nx0, nx1, nx2, nx3;
    const bool have = (ph+1 < NPH);
    if (have){
      const unsigned short* nb = sb + (size_t)((ph+1)*64)*WD;
      nx0 = *(const uint4*)(nb + (size_t)( 0)*WD);
      nx1 = *(const uint4*)(nb + (size_t)(16)*WD);
      nx2 = *(const uint4*)(nb + (size_t)(32)*WD);
      nx3 = *(const uint4*)(nb + (size_t)(48)*WD);
    }
    #pragma unroll
    for (int s = 0; s < 4; s++){
      const int tt = ph*4 + s;
      const int jb = j0 + tt*16;
      const unsigned lw = ldslab[tt*4 + lg];
      const int b0 = (int)(lw&255u),       b1 = (int)((lw>>8)&255u);
      const int b2 = (int)((lw>>16)&255u), b3 = (int)(lw>>24);
      const int rl = s*16 + ln;
      const unsigned rbase = rl*PITCH + lg*16;
      short8v af0 = *(const short8v*)&atile[cur][rbase +   0];
      short8v af1 = *(const short8v*)&atile[cur][rbase +  64];
      short8v af2 = *(const short8v*)&atile[cur][rbase + 128];
      short8v af3 = *(const short8v*)&atile[cur][rbase + 192];
      #pragma unroll
      for (int ss = 0; ss < 2; ss++){
        float4v acc = {0.f,0.f,0.f,0.f};
        acc = __builtin_amdgcn_mfma_f32_16x16x32_bf16(af0, bf[ss][0], acc, 0,0,0);
        acc = __builtin_amdgcn_mfma_f32_16x16x32_bf16(af1, bf[ss][1], acc, 0,0,0);
        acc = __builtin_amdgcn_mfma_f32_16x16x32_bf16(af2, bf[ss][2], acc, 0,0,0);
        acc = __builtin_amdgcn_mfma_f32_16x16x32_bf16(af3, bf[ss][3], acc, 0,0,0);
        float v0 = acc[0], v1 = acc[1], v2 = acc[2], v3 = acc[3];
        ps[ss] += ((b0==labA[ss]) ? v0 : 0.f) + ((b1==labA[ss]) ? v1 : 0.f)
                + ((b2==labA[ss]) ? v2 : 0.f) + ((b3==labA[ss]) ? v3 : 0.f);
        if (DIAG && jb == awave + ss*16){   // wave-uniform; self always matches
          const int r0 = lg*4;
          if (r0+0 == ln){ ps[ss] -= v0; v0 = -INFINITY; }
          if (r0+1 == ln){ ps[ss] -= v1; v1 = -INFINITY; }
          if (r0+2 == ln){ ps[ss] -= v2; v2 = -INFINITY; }
          if (r0+3 == ln){ ps[ss] -= v3; v3 = -INFINITY; }
        }
        float tmax = fmaxf(fmaxf(v0,v1), fmaxf(v2,v3));
        float mn = fmaxf(m[ss], tmax);
        l[ss] = l[ss]*EXP2(m[ss]-mn)
              + ((EXP2(v0-mn) + EXP2(v1-mn)) + (EXP2(v2-mn) + EXP2(v3-mn)));
        m[ss] = mn;
      }
    }
    if (have){
      *(uint4*)&atile[cur^1][swbase +  0*PITCH] = nx0;
      *(uint4*)&atile[cur^1][swbase + 16*PITCH] = nx1;
      *(uint4*)&atile[cur^1][swbase + 32*PITCH] = nx2;
      *(uint4*)&atile[cur^1][swbase + 48*PITCH] = nx3;
    }
    __syncthreads();
  }

  // combine lanes {x^16, x^32} (same anchor, different j-row groups)
  #pragma unroll
  for (int ss = 0; ss < 2; ss++){
    float mm = m[ss], ll = l[ss], pp = ps[ss];
    #pragma unroll
    for (int off = 16; off < 64; off <<= 1){
      float mo = __shfl_xor(mm, off);
      float lo = __shfl_xor(ll, off);
      float M = fmaxf(mm, mo);
      ll = ll*EXP2(mm-M) + lo*EXP2(mo-M);
      mm = M;
      pp += __shfl_xor(pp, off);
    }
    if (lane < 16){
      size_t o = (size_t)split*WB + awave + ss*16 + lane;
      partM[o] = mm; partL[o] = ll; partPS[o] = pp;
    }
  }
}

// 32 blocks x 256 threads: one anchor per thread.
__global__ __launch_bounds__(256) void k_final(const int* __restrict__ labels,
                                               const int* __restrict__ cntpart,
                                               const float* __restrict__ partM,
                                               const float* __restrict__ partL,
                                               const float* __restrict__ partPS,
                                               float* accf, int* accn, int* ticket,
                                               float* __restrict__ out){
  const int t = threadIdx.x;
  const int a = blockIdx.x*256 + t;
  float mm = -INFINITY;
  #pragma unroll 8
  for (int sp = 0; sp < NSPLIT; sp++)
    mm = fmaxf(mm, partM[(size_t)sp*WB + a]);
  float ll = 0.f, pp = 0.f;
  #pragma unroll 8
  for (int sp = 0; sp < NSPLIT; sp++){
    ll = fmaf(partL[(size_t)sp*WB + a], EXP2(partM[(size_t)sp*WB + a] - mm), ll);
    pp += partPS[(size_t)sp*WB + a];
  }
  float lse2 = mm + LOG2(ll);             // log2 units
  int lab = labels[a];
  int c = 0;
  #pragma unroll
  for (int b = 0; b < 8; b++) c += cntpart[b*128 + lab];
  int np = c - 1;
  float loss = 0.f, val = 0.f;
  if (np > 0){ loss = LN2F*(lse2 - pp/(float)np); val = 1.f; }
  #pragma unroll
  for (int off = 32; off > 0; off >>= 1){
    loss += __shfl_down(loss, off);
    val  += __shfl_down(val,  off);
  }
  __shared__ float sl[4], sv[4];
  int wv = t>>6, lane = t&63;
  if (lane == 0){ sl[wv] = loss; sv[wv] = val; }
  __syncthreads();
  if (t == 0){
    atomicAdd(accf, sl[0]+sl[1]+sl[2]+sl[3]);
    atomicAdd(accn, (int)(sv[0]+sv[1]+sv[2]+sv[3] + 0.5f));
    __threadfence();
    int tk = atomicAdd(ticket, 1);
    if (tk == 31){                         // last block finalizes
      float f = atomicAdd(accf, 0.f);
      int   n = atomicAdd(accn, 0);
      out[0] = f / (float)max(n, 1);
    }
  }
}

extern "C" void kernel_launch(void* const* d_in, const int* in_sizes, int n_in,
                              void* d_out, int out_size, void* d_ws, size_t ws_size,
                              hipStream_t stream){
  const float* z = (const float*)d_in[0];
  const int* labels = (const int*)d_in[1];
  char* ws = (char*)d_ws;
  unsigned short* zbf = (unsigned short*)(ws + WS_ZBF);
  int*      cntp   = (int*)(ws + WS_CNTP);
  float*    accf   = (float*)(ws + WS_ACC);
  int*      accn   = (int*)(ws + WS_ACC + 4);
  int*      ticket = (int*)(ws + WS_ACC + 8);
  unsigned* labu8  = (unsigned*)(ws + WS_LAB);
  float*    partM  = (float*)(ws + WS_PM);
  float*    partL  = (float*)(ws + WS_PL);
  float*    partPS = (float*)(ws + WS_PP);
  float* out = (float*)d_out;

  hipLaunchKernelGGL(k_prep,  dim3(520),  dim3(256), 0, stream,
                     z, labels, zbf, labu8, cntp, accf, accn, ticket);
  hipLaunchKernelGGL(k_lse,   dim3(1024), dim3(256), 0, stream,
                     zbf, labels, labu8, partM, partL, partPS);
  hipLaunchKernelGGL(k_final, dim3(32),   dim3(256), 0, stream,
                     labels, cntp, partM, partL, partPS, accf, accn, ticket, out);
}